// Round 7
// baseline (881.384 us; speedup 1.0000x reference)
//
#include <hip/hip_runtime.h>

// Deformable conv fusion v7: v6 + in-block split-K x2 (4 waves/SIMD).
// - 1024 blocks x 256 thr; wave = (nh, kpar): 32px x 128oc x 36 chunks.
// - Phase A computed once per block into shared LDS (wv0/wv1).
// - kpar=1 waves reduce into LDS (reused off region); kpar=0 add+ReLU+store.
// - Main loop body identical to v6 (NHWC bf16 gathers, ping-pong B-frags).

constexpr int H_ = 64, W_ = 256;
constexpr int HWsz = H_ * W_;
constexpr int OC_ = 256;
constexpr int WMAIN_ELEMS = 72 * 16 * 64 * 8;
constexpr int WOFFB_ELEMS = 8 * 5 * 64 * 8;
constexpr size_t XT_ELEMS = (size_t)8 * HWsz * 64;   // [bg 8][y][x][c 64] bf16

using f32x4 = __attribute__((ext_vector_type(4))) float;
using s16x8 = __attribute__((ext_vector_type(8))) short;
using u16x8 = __attribute__((ext_vector_type(8))) unsigned short;

__device__ __forceinline__ unsigned short f2bf(float f) {
    unsigned u = __float_as_uint(f);
    return (unsigned short)((u + 0x7fffu + ((u >> 16) & 1u)) >> 16);
}
__device__ __forceinline__ float bf2f(unsigned short u) {
    return __uint_as_float((unsigned)u << 16);
}

// ---------------- prep kernels (unchanged from v6) ----------------

__global__ __launch_bounds__(256) void wprep_kernel(const float* __restrict__ w_def,
                                                    const float* __restrict__ w_off,
                                                    unsigned short* __restrict__ w2) {
    int i = blockIdx.x * 256 + threadIdx.x;
    if (i < WMAIN_ELEMS) {
        int j = i & 7, lane = (i >> 3) & 63, t = (i >> 9) & 15, gkh = i >> 13;
        int half = gkh & 1, gk = gkh >> 1;
        int k = gk % 9, g = gk / 9;
        int oc = t * 16 + (lane & 15);
        int cin = g * 64 + half * 32 + (lane >> 4) * 8 + j;
        w2[i] = f2bf(w_def[(size_t)oc * 2304 + (size_t)cin * 9 + k]);
    } else if (i < WMAIN_ELEMS + WOFFB_ELEMS) {
        int i2 = i - WMAIN_ELEMS;
        int j = i2 & 7, lane = (i2 >> 3) & 63, idx = i2 >> 9;   // idx = c8*5 + t
        int t = idx % 5, c8 = idx / 5;
        int o = t * 16 + (lane & 15);
        int ch = c8 * 32 + (lane >> 4) * 8 + j;
        float v = (o < 72) ? w_off[o * 256 + ch] : 0.f;
        w2[i] = f2bf(v);
    }
}

__global__ __launch_bounds__(256) void xprep_kernel(const float* __restrict__ x0,
                                                    const float* __restrict__ x1,
                                                    const float* __restrict__ x2,
                                                    unsigned short* __restrict__ xt) {
    __shared__ unsigned short tl[256][66];
    const int bg = blockIdx.x >> 6;
    const int y  = blockIdx.x & 63;
    const int b  = bg >> 2, g = bg & 3;
    const int tid = threadIdx.x;
    const float* src = (g == 0) ? x0 + (size_t)b * 64 * HWsz
                     : (g == 1) ? x1 + (size_t)b * 64 * HWsz
                     : x2 + (size_t)b * 128 * HWsz + (size_t)(g - 2) * 64 * HWsz;
    src += y * W_;
    for (int c = 0; c < 64; ++c)
        tl[tid][c] = f2bf(src[(size_t)c * HWsz + tid]);
    __syncthreads();
    unsigned short* dst = xt + ((size_t)bg * HWsz + y * W_) * 64;
    #pragma unroll
    for (int s = 0; s < 8; ++s) {
        int si = s * 256 + tid;
        int px = si >> 3, q = si & 7;
        u16x8 v;
        #pragma unroll
        for (int j = 0; j < 8; ++j) v[j] = tl[px][q * 8 + j];
        *(u16x8*)(dst + (size_t)px * 64 + q * 8) = v;
    }
}

// ---------------- main kernel helpers ----------------

struct GeomT {
    float w00, w01, w10, w11;
    int o00, o01, o10, o11;
    const unsigned short* base;
};

__device__ __forceinline__ GeomT make_geomT(
    int gkh, const float* offp, int h, int xcoord, int pgp, int cq,
    const unsigned short* xtb)
{
    const int half = gkh & 1, gk = gkh >> 1;
    const int k = gk % 9, g = gk / 9;
    const int ky = k / 3, kx = k % 3;
    float dy = offp[(2 * gk) * 32 + pgp];
    float dx = offp[(2 * gk + 1) * 32 + pgp];
    float fy = (float)(h - 1 + ky) + dy;
    float fx = (float)(xcoord - 1 + kx) + dx;
    float y0f = floorf(fy), x0f = floorf(fx);
    float wy = fy - y0f, wx = fx - x0f;
    int iy0 = (int)y0f, ix0 = (int)x0f;
    int iy1 = iy0 + 1, ix1 = ix0 + 1;
    float vy0 = (iy0 >= 0 && iy0 < H_) ? 1.f : 0.f;
    float vy1 = (iy1 >= 0 && iy1 < H_) ? 1.f : 0.f;
    float vx0 = (ix0 >= 0 && ix0 < W_) ? 1.f : 0.f;
    float vx1 = (ix1 >= 0 && ix1 < W_) ? 1.f : 0.f;
    GeomT gm;
    gm.w00 = (1.f - wy) * (1.f - wx) * vy0 * vx0;
    gm.w01 = (1.f - wy) * wx * vy0 * vx1;
    gm.w10 = wy * (1.f - wx) * vy1 * vx0;
    gm.w11 = wy * wx * vy1 * vx1;
    int cy0 = min(max(iy0, 0), H_ - 1), cy1 = min(max(iy1, 0), H_ - 1);
    int cx0 = min(max(ix0, 0), W_ - 1), cx1 = min(max(ix1, 0), W_ - 1);
    int ch = half * 32 + cq * 8;
    gm.o00 = (cy0 * W_ + cx0) * 64 + ch;
    gm.o01 = (cy0 * W_ + cx1) * 64 + ch;
    gm.o10 = (cy1 * W_ + cx0) * 64 + ch;
    gm.o11 = (cy1 * W_ + cx1) * 64 + ch;
    gm.base = xtb + (size_t)g * HWsz * 64;
    return gm;
}

__device__ __forceinline__ void load_corners(const GeomT& g0, const GeomT& g1,
                                             u16x8 (&C)[8]) {
    C[0] = *(const u16x8*)(g0.base + g0.o00);
    C[1] = *(const u16x8*)(g0.base + g0.o01);
    C[2] = *(const u16x8*)(g0.base + g0.o10);
    C[3] = *(const u16x8*)(g0.base + g0.o11);
    C[4] = *(const u16x8*)(g1.base + g1.o00);
    C[5] = *(const u16x8*)(g1.base + g1.o01);
    C[6] = *(const u16x8*)(g1.base + g1.o10);
    C[7] = *(const u16x8*)(g1.base + g1.o11);
}

__device__ __forceinline__ s16x8 combine4(const u16x8& c00, const u16x8& c01,
                                          const u16x8& c10, const u16x8& c11,
                                          float w00, float w01, float w10, float w11) {
    s16x8 a;
    #pragma unroll
    for (int j = 0; j < 8; ++j) {
        float v = fmaf(w00, bf2f(c00[j]), fmaf(w01, bf2f(c01[j]),
                  fmaf(w10, bf2f(c10[j]), w11 * bf2f(c11[j]))));
        a[j] = (short)f2bf(v);
    }
    return a;
}

__device__ __forceinline__ void load_bfrag(const unsigned short* w2c, s16x8 (&B)[8]) {
    #pragma unroll
    for (int t = 0; t < 8; ++t) B[t] = *(const s16x8*)(w2c + t * 512);
}

__device__ __forceinline__ void mfma8(const s16x8& a, const s16x8 (&B)[8],
                                      f32x4 (&acc)[8]) {
    #pragma unroll
    for (int t = 0; t < 8; ++t)
        acc[t] = __builtin_amdgcn_mfma_f32_16x16x32_bf16(a, B[t], acc[t], 0, 0, 0);
}

// ---------------- main kernel (tier 2): split-K x2 ----------------

__global__ __launch_bounds__(256, 4) void deform32k_kernel(
    const unsigned short* __restrict__ xt, const float* __restrict__ b_off,
    const unsigned short* __restrict__ w2, float* __restrict__ out)
{
    // shmem: [0, 2304) = off[72][32] during phases A/B;
    // after main-loop barrier: full 8192 floats = split-K reduction buffer.
    __shared__ __align__(16) float shmem[8192];   // 32 KB

    const int tid  = threadIdx.x;
    const int lane = tid & 63;
    const int wv   = tid >> 6;              // 0..3
    const int nh   = wv & 1;                // oc half
    const int kp   = wv >> 1;               // chunk parity
    // XCD swizzle: 1024 = 8 * 128
    const int bid  = ((blockIdx.x & 7) << 7) | (blockIdx.x >> 3);
    const int xq   = bid & 7;
    const int h    = (bid >> 3) & 63;
    const int b    = bid >> 9;
    const int p16  = lane & 15;
    const int cq   = lane >> 4;
    const int wbase = xq * 32;

    const unsigned short* xtb = xt + (size_t)b * 4 * HWsz * 64;

    // ---- Phase A: offsets via MFMA, once per block (wv0->pg0, wv1->pg1) ----
    if (wv < 2) {
        const int pg = wv;
        f32x4 oa[5];
        #pragma unroll
        for (int t = 0; t < 5; ++t) {
            int o = t * 16 + p16;
            float bv = (o < 72) ? b_off[o] : 0.f;
            oa[t][0] = bv; oa[t][1] = bv; oa[t][2] = bv; oa[t][3] = bv;
        }
        const int pixg = h * W_ + wbase + pg * 16;
        #pragma unroll
        for (int c8 = 0; c8 < 8; ++c8) {
            const unsigned short* ap = xtb + (size_t)(c8 >> 1) * HWsz * 64
                                     + (size_t)(pixg + p16) * 64 + (c8 & 1) * 32 + cq * 8;
            s16x8 a = *(const s16x8*)ap;
            const unsigned short* wb = w2 + WMAIN_ELEMS + (size_t)(c8 * 5) * 512;
            #pragma unroll
            for (int t = 0; t < 5; ++t) {
                s16x8 bf = *(const s16x8*)(wb + t * 512 + lane * 8);
                oa[t] = __builtin_amdgcn_mfma_f32_16x16x32_bf16(a, bf, oa[t], 0, 0, 0);
            }
        }
        #pragma unroll
        for (int t = 0; t < 5; ++t) {
            int o = t * 16 + p16;
            if (o < 72) {
                #pragma unroll
                for (int r = 0; r < 4; ++r)
                    shmem[o * 32 + pg * 16 + cq * 4 + r] = oa[t][r];
            }
        }
    }
    __syncthreads();

    // ---- Phase B: 36 chunks per wave (parity kp), ping-pong B ----
    f32x4 accP[8], accQ[8];
    #pragma unroll
    for (int t = 0; t < 8; ++t) {
        accP[t][0]=0;accP[t][1]=0;accP[t][2]=0;accP[t][3]=0;
        accQ[t][0]=0;accQ[t][1]=0;accQ[t][2]=0;accQ[t][3]=0;
    }

    const float* offp = shmem;
    const int xc0 = wbase + p16, xc1 = wbase + 16 + p16;
    const unsigned short* w2m = w2 + nh * 4096 + lane * 8;

    GeomT gm0 = make_geomT(kp, offp, h, xc0, p16, cq, xtb);
    GeomT gm1 = make_geomT(kp, offp, h, xc1, 16 + p16, cq, xtb);
    u16x8 C[8];
    s16x8 Ba[8], Bb[8];
    load_corners(gm0, gm1, C);
    load_bfrag(w2m + (size_t)kp * 8192, Ba);

    for (int it = 0; it < 18; ++it) {
        {   // chunk kp + 4*it : use Ba, prefetch chunk kp + 4*it + 2 into Bb
            s16x8 a0 = combine4(C[0], C[1], C[2], C[3], gm0.w00, gm0.w01, gm0.w10, gm0.w11);
            s16x8 a1 = combine4(C[4], C[5], C[6], C[7], gm1.w00, gm1.w01, gm1.w10, gm1.w11);
            __builtin_amdgcn_sched_barrier(0);
            const int gn = kp + 4 * it + 2;
            gm0 = make_geomT(gn, offp, h, xc0, p16, cq, xtb);
            gm1 = make_geomT(gn, offp, h, xc1, 16 + p16, cq, xtb);
            load_corners(gm0, gm1, C);
            load_bfrag(w2m + (size_t)gn * 8192, Bb);
            __builtin_amdgcn_sched_barrier(0);
            mfma8(a0, Ba, accP);
            mfma8(a1, Ba, accQ);
        }
        {   // chunk kp + 4*it + 2 : use Bb, prefetch next into Ba
            s16x8 a0 = combine4(C[0], C[1], C[2], C[3], gm0.w00, gm0.w01, gm0.w10, gm0.w11);
            s16x8 a1 = combine4(C[4], C[5], C[6], C[7], gm1.w00, gm1.w01, gm1.w10, gm1.w11);
            __builtin_amdgcn_sched_barrier(0);
            const int gn = (it < 17) ? kp + 4 * it + 4 : kp + 4 * it + 2;  // tail dummy
            gm0 = make_geomT(gn, offp, h, xc0, p16, cq, xtb);
            gm1 = make_geomT(gn, offp, h, xc1, 16 + p16, cq, xtb);
            load_corners(gm0, gm1, C);
            load_bfrag(w2m + (size_t)gn * 8192, Ba);
            __builtin_amdgcn_sched_barrier(0);
            mfma8(a0, Bb, accP);
            mfma8(a1, Bb, accQ);
        }
    }

    // ---- split-K reduction: kp=1 waves -> LDS -> kp=0 waves ----
    __syncthreads();   // all off/geom reads done; shmem is now the red buffer
    if (kp == 1) {
        float* red = shmem + nh * 4096;
        #pragma unroll
        for (int t = 0; t < 8; ++t) {
            *(f32x4*)(red + t * 256 + lane * 4) = accP[t];
            *(f32x4*)(red + (t + 8) * 256 + lane * 4) = accQ[t];
        }
    }
    __syncthreads();

    // ---- epilogue: add + ReLU + float4 stores (kp=0 waves) ----
    if (kp == 0) {
        const float* red = shmem + nh * 4096;
        const size_t obase = (size_t)b * OC_ * HWsz + (size_t)h * W_ + wbase + cq * 4;
        #pragma unroll
        for (int t = 0; t < 8; ++t) {
            f32x4 rP = *(const f32x4*)(red + t * 256 + lane * 4);
            f32x4 rQ = *(const f32x4*)(red + (t + 8) * 256 + lane * 4);
            int oc = nh * 128 + t * 16 + p16;
            float4 r0, r1;
            r0.x = fmaxf(accP[t][0] + rP[0], 0.f); r0.y = fmaxf(accP[t][1] + rP[1], 0.f);
            r0.z = fmaxf(accP[t][2] + rP[2], 0.f); r0.w = fmaxf(accP[t][3] + rP[3], 0.f);
            r1.x = fmaxf(accQ[t][0] + rQ[0], 0.f); r1.y = fmaxf(accQ[t][1] + rQ[1], 0.f);
            r1.z = fmaxf(accQ[t][2] + rQ[2], 0.f); r1.w = fmaxf(accQ[t][3] + rQ[3], 0.f);
            *(float4*)(out + obase + (size_t)oc * HWsz) = r0;
            *(float4*)(out + obase + (size_t)oc * HWsz + 16) = r1;
        }
    }
}

// ---------------- tier-1/0 fallback (v5 kernel, verified) ----------------

struct Geom {
    float w00, w01, w10, w11;
    int o00, o01, o10, o11;
    const float* base;
};

__device__ __forceinline__ Geom make_geom(
    int gkh, const float* offp, int h, int wbase, int p, int cq,
    const float* xA, const float* xB, const float* xC)
{
    const int half = gkh & 1, gk = gkh >> 1;
    const int k = gk % 9, g = gk / 9;
    const int ky = k / 3, kx = k % 3;
    float dy = offp[(2 * gk) * 16 + p];
    float dx = offp[(2 * gk + 1) * 16 + p];
    float fy = (float)(h - 1 + ky) + dy;
    float fx = (float)(wbase + p - 1 + kx) + dx;
    float y0f = floorf(fy), x0f = floorf(fx);
    float wy = fy - y0f, wx = fx - x0f;
    int iy0 = (int)y0f, ix0 = (int)x0f;
    int iy1 = iy0 + 1, ix1 = ix0 + 1;
    float vy0 = (iy0 >= 0 && iy0 < H_) ? 1.f : 0.f;
    float vy1 = (iy1 >= 0 && iy1 < H_) ? 1.f : 0.f;
    float vx0 = (ix0 >= 0 && ix0 < W_) ? 1.f : 0.f;
    float vx1 = (ix1 >= 0 && ix1 < W_) ? 1.f : 0.f;
    Geom gm;
    gm.w00 = (1.f - wy) * (1.f - wx) * vy0 * vx0;
    gm.w01 = (1.f - wy) * wx * vy0 * vx1;
    gm.w10 = wy * (1.f - wx) * vy1 * vx0;
    gm.w11 = wy * wx * vy1 * vx1;
    int cy0 = min(max(iy0, 0), H_ - 1), cy1 = min(max(iy1, 0), H_ - 1);
    int cx0 = min(max(ix0, 0), W_ - 1), cx1 = min(max(ix1, 0), W_ - 1);
    int choff = (half * 32 + cq * 8) * HWsz;
    gm.o00 = choff + cy0 * W_ + cx0;
    gm.o01 = choff + cy0 * W_ + cx1;
    gm.o10 = choff + cy1 * W_ + cx0;
    gm.o11 = choff + cy1 * W_ + cx1;
    gm.base = (g == 0) ? xA : (g == 1) ? xB : (g == 2) ? xC : xC + (size_t)64 * HWsz;
    return gm;
}

#define GATHER(J, Cv) do { \
    Cv.x = gm.base[gm.o00 + (J) * HWsz]; \
    Cv.y = gm.base[gm.o01 + (J) * HWsz]; \
    Cv.z = gm.base[gm.o10 + (J) * HWsz]; \
    Cv.w = gm.base[gm.o11 + (J) * HWsz]; \
} while (0)

#define COMB(Cv, IDX) \
    a[IDX] = (short)f2bf(fmaf(w00c, Cv.x, fmaf(w01c, Cv.y, fmaf(w10c, Cv.z, w11c * Cv.w))))

template<bool USE_WS>
__global__ __launch_bounds__(128, 3) void deform_kernel(
    const float* __restrict__ x0, const float* __restrict__ x1,
    const float* __restrict__ x2,
    const float* __restrict__ w_off, const float* __restrict__ b_off,
    const float* __restrict__ w_def, const unsigned short* __restrict__ w2,
    float* __restrict__ out)
{
    __shared__ float off_lds[2][72 * 16];

    const int tid  = threadIdx.x;
    const int lane = tid & 63;
    const int wv   = tid >> 6;
    const int bid  = ((blockIdx.x & 7) << 8) | (blockIdx.x >> 3);
    const int nh   = wv;
    const int ws_  = bid & 15;
    const int h    = (bid >> 4) & 63;
    const int b    = bid >> 10;
    const int p    = lane & 15;
    const int cq   = lane >> 4;
    const int wbase = ws_ * 16;
    const int pix  = h * W_ + wbase;

    const float* xA = x0 + (size_t)b * 64  * HWsz;
    const float* xB = x1 + (size_t)b * 64  * HWsz;
    const float* xC = x2 + (size_t)b * 128 * HWsz;

    f32x4 oa[5];
    #pragma unroll
    for (int t = 0; t < 5; ++t) {
        int o = t * 16 + p;
        float bv = (o < 72) ? b_off[o] : 0.f;
        oa[t][0] = bv; oa[t][1] = bv; oa[t][2] = bv; oa[t][3] = bv;
    }
    #pragma unroll
    for (int c8 = 0; c8 < 8; ++c8) {
        const float* src = (c8 < 2) ? xA + (size_t)c8 * 32 * HWsz
                         : (c8 < 4) ? xB + (size_t)(c8 - 2) * 32 * HWsz
                                    : xC + (size_t)(c8 - 4) * 32 * HWsz;
        s16x8 a;
        #pragma unroll
        for (int j = 0; j < 8; ++j)
            a[j] = (short)f2bf(src[(cq * 8 + j) * HWsz + pix + p]);
        #pragma unroll
        for (int t = 0; t < 5; ++t) {
            int o = t * 16 + p;
            s16x8 bf;
            if (USE_WS) {
                bf = *(const s16x8*)(w2 + WMAIN_ELEMS + (size_t)(c8 * 5 + t) * 512 + lane * 8);
            } else {
                #pragma unroll
                for (int j = 0; j < 8; ++j)
                    bf[j] = (o < 72) ? (short)f2bf(w_off[o * 256 + c8 * 32 + cq * 8 + j])
                                     : (short)0;
            }
            oa[t] = __builtin_amdgcn_mfma_f32_16x16x32_bf16(a, bf, oa[t], 0, 0, 0);
        }
    }
    #pragma unroll
    for (int t = 0; t < 5; ++t) {
        int o = t * 16 + p;
        if (o < 72) {
            #pragma unroll
            for (int r = 0; r < 4; ++r)
                off_lds[wv][o * 16 + cq * 4 + r] = oa[t][r];
        }
    }

    f32x4 acc0={0,0,0,0},acc1={0,0,0,0},acc2={0,0,0,0},acc3={0,0,0,0};
    f32x4 acc4={0,0,0,0},acc5={0,0,0,0},acc6={0,0,0,0},acc7={0,0,0,0};
    const float* offp = &off_lds[wv][0];

    for (int gkh = 0; gkh < 72; ++gkh) {
        Geom gm = make_geom(gkh, offp, h, wbase, p, cq, xA, xB, xC);
        float4 c0, c1, c2, c3, c4, c5, c6, c7;
        GATHER(0, c0); GATHER(1, c1); GATHER(2, c2); GATHER(3, c3);
        GATHER(4, c4); GATHER(5, c5); GATHER(6, c6); GATHER(7, c7);
        float w00c = gm.w00, w01c = gm.w01, w10c = gm.w10, w11c = gm.w11;
        s16x8 a;
        COMB(c0, 0); COMB(c1, 1); COMB(c2, 2); COMB(c3, 3);
        COMB(c4, 4); COMB(c5, 5); COMB(c6, 6); COMB(c7, 7);
        const int half = gkh & 1, gk = gkh >> 1;
        const int k = gk % 9, g = gk / 9;
        const int cbase = g * 64 + half * 32 + cq * 8;
        f32x4* accp[8] = {&acc0,&acc1,&acc2,&acc3,&acc4,&acc5,&acc6,&acc7};
        #pragma unroll
        for (int t = 0; t < 8; ++t) {
            int oc = nh * 128 + t * 16 + p;
            s16x8 bf;
            if (USE_WS) {
                bf = *(const s16x8*)(w2 + gkh * 8192 + nh * 4096 + t * 512 + lane * 8);
            } else {
                #pragma unroll
                for (int j = 0; j < 8; ++j)
                    bf[j] = (short)f2bf(w_def[(size_t)oc * 2304 + (size_t)(cbase + j) * 9 + k]);
            }
            *accp[t] = __builtin_amdgcn_mfma_f32_16x16x32_bf16(a, bf, *accp[t], 0, 0, 0);
        }
    }

    const size_t obase = (size_t)b * OC_ * HWsz + (size_t)h * W_ + wbase + cq * 4;
    f32x4 accs[8] = {acc0, acc1, acc2, acc3, acc4, acc5, acc6, acc7};
    #pragma unroll
    for (int t = 0; t < 8; ++t) {
        int oc = nh * 128 + t * 16 + p;
        float4 r;
        r.x = fmaxf(accs[t][0], 0.f);
        r.y = fmaxf(accs[t][1], 0.f);
        r.z = fmaxf(accs[t][2], 0.f);
        r.w = fmaxf(accs[t][3], 0.f);
        *(float4*)(out + obase + (size_t)oc * HWsz) = r;
    }
}

extern "C" void kernel_launch(void* const* d_in, const int* in_sizes, int n_in,
                              void* d_out, int out_size, void* d_ws, size_t ws_size,
                              hipStream_t stream) {
    const float* x0    = (const float*)d_in[0];
    const float* x1    = (const float*)d_in[1];
    const float* x2    = (const float*)d_in[2];
    const float* w_off = (const float*)d_in[3];
    const float* b_off = (const float*)d_in[4];
    const float* w_def = (const float*)d_in[5];
    float* out = (float*)d_out;

    const size_t w2_bytes   = (size_t)(WMAIN_ELEMS + WOFFB_ELEMS) * 2;
    const size_t full_bytes = (XT_ELEMS + WMAIN_ELEMS + WOFFB_ELEMS) * 2;   // ~18 MB

    if (ws_size >= full_bytes) {
        unsigned short* xt = (unsigned short*)d_ws;
        unsigned short* w2 = xt + XT_ELEMS;
        hipLaunchKernelGGL(xprep_kernel, dim3(512), dim3(256), 0, stream, x0, x1, x2, xt);
        hipLaunchKernelGGL(wprep_kernel, dim3((WMAIN_ELEMS + WOFFB_ELEMS) / 256), dim3(256),
                           0, stream, w_def, w_off, w2);
        hipLaunchKernelGGL(deform32k_kernel, dim3(1024), dim3(256), 0, stream,
                           xt, b_off, w2, out);
    } else if (ws_size >= w2_bytes) {
        unsigned short* w2 = (unsigned short*)d_ws;
        hipLaunchKernelGGL(wprep_kernel, dim3((WMAIN_ELEMS + WOFFB_ELEMS) / 256), dim3(256),
                           0, stream, w_def, w_off, w2);
        hipLaunchKernelGGL((deform_kernel<true>), dim3(2048), dim3(128), 0, stream,
                           x0, x1, x2, w_off, b_off, w_def, w2, out);
    } else {
        hipLaunchKernelGGL((deform_kernel<false>), dim3(2048), dim3(128), 0, stream,
                           x0, x1, x2, w_off, b_off, w_def, (const unsigned short*)nullptr, out);
    }
}

// Round 8
// 184.117 us; speedup vs baseline: 4.7871x; 4.7871x over previous
//
#include <hip/hip_runtime.h>

// Deformable conv fusion v8: v6 + depth-2 corner prefetch pipeline.
// - 1024 blocks x 128 thr (2 waves: nh 0/1 of one 32px tile), XCD swizzle.
// - Per chunk: combine(corners prefetched 2 chunks ago) -> issue w-frags ->
//   issue corners(i+2) -> 16 MFMA. sched_barrier(0) pins issue order so the
//   MFMA's vmcnt wait (w-frags) never drains the in-flight corner prefetch.
// - Registers: ~64 acc + 64 corners(2 sets) + 32 wf + geom ~ 200 < 256 cap
//   (launch_bounds(128,2)) -- no spill (tripwire: WRITE_SIZE ~33 MB).

constexpr int H_ = 64, W_ = 256;
constexpr int HWsz = H_ * W_;
constexpr int OC_ = 256;
constexpr int WMAIN_ELEMS = 72 * 16 * 64 * 8;
constexpr int WOFFB_ELEMS = 8 * 5 * 64 * 8;
constexpr size_t XT_ELEMS = (size_t)8 * HWsz * 64;   // [bg 8][y][x][c 64] bf16

using f32x4 = __attribute__((ext_vector_type(4))) float;
using s16x8 = __attribute__((ext_vector_type(8))) short;
using u16x8 = __attribute__((ext_vector_type(8))) unsigned short;

__device__ __forceinline__ unsigned short f2bf(float f) {
    unsigned u = __float_as_uint(f);
    return (unsigned short)((u + 0x7fffu + ((u >> 16) & 1u)) >> 16);
}
__device__ __forceinline__ float bf2f(unsigned short u) {
    return __uint_as_float((unsigned)u << 16);
}

// ---------------- prep kernels (unchanged, verified) ----------------

__global__ __launch_bounds__(256) void wprep_kernel(const float* __restrict__ w_def,
                                                    const float* __restrict__ w_off,
                                                    unsigned short* __restrict__ w2) {
    int i = blockIdx.x * 256 + threadIdx.x;
    if (i < WMAIN_ELEMS) {
        int j = i & 7, lane = (i >> 3) & 63, t = (i >> 9) & 15, gkh = i >> 13;
        int half = gkh & 1, gk = gkh >> 1;
        int k = gk % 9, g = gk / 9;
        int oc = t * 16 + (lane & 15);
        int cin = g * 64 + half * 32 + (lane >> 4) * 8 + j;
        w2[i] = f2bf(w_def[(size_t)oc * 2304 + (size_t)cin * 9 + k]);
    } else if (i < WMAIN_ELEMS + WOFFB_ELEMS) {
        int i2 = i - WMAIN_ELEMS;
        int j = i2 & 7, lane = (i2 >> 3) & 63, idx = i2 >> 9;   // idx = c8*5 + t
        int t = idx % 5, c8 = idx / 5;
        int o = t * 16 + (lane & 15);
        int ch = c8 * 32 + (lane >> 4) * 8 + j;
        float v = (o < 72) ? w_off[o * 256 + ch] : 0.f;
        w2[i] = f2bf(v);
    }
}

__global__ __launch_bounds__(256) void xprep_kernel(const float* __restrict__ x0,
                                                    const float* __restrict__ x1,
                                                    const float* __restrict__ x2,
                                                    unsigned short* __restrict__ xt) {
    __shared__ unsigned short tl[256][66];
    const int bg = blockIdx.x >> 6;
    const int y  = blockIdx.x & 63;
    const int b  = bg >> 2, g = bg & 3;
    const int tid = threadIdx.x;
    const float* src = (g == 0) ? x0 + (size_t)b * 64 * HWsz
                     : (g == 1) ? x1 + (size_t)b * 64 * HWsz
                     : x2 + (size_t)b * 128 * HWsz + (size_t)(g - 2) * 64 * HWsz;
    src += y * W_;
    for (int c = 0; c < 64; ++c)
        tl[tid][c] = f2bf(src[(size_t)c * HWsz + tid]);
    __syncthreads();
    unsigned short* dst = xt + ((size_t)bg * HWsz + y * W_) * 64;
    #pragma unroll
    for (int s = 0; s < 8; ++s) {
        int si = s * 256 + tid;
        int px = si >> 3, q = si & 7;
        u16x8 v;
        #pragma unroll
        for (int j = 0; j < 8; ++j) v[j] = tl[px][q * 8 + j];
        *(u16x8*)(dst + (size_t)px * 64 + q * 8) = v;
    }
}

// ---------------- main kernel helpers ----------------

struct GeomT {
    float w00, w01, w10, w11;
    int o00, o01, o10, o11;
    const unsigned short* base;
};

__device__ __forceinline__ GeomT make_geomT(
    int gkh, const float* offp, int h, int xcoord, int pgp, int cq,
    const unsigned short* xtb)
{
    const int half = gkh & 1, gk = gkh >> 1;
    const int k = gk % 9, g = gk / 9;
    const int ky = k / 3, kx = k % 3;
    float dy = offp[(2 * gk) * 32 + pgp];
    float dx = offp[(2 * gk + 1) * 32 + pgp];
    float fy = (float)(h - 1 + ky) + dy;
    float fx = (float)(xcoord - 1 + kx) + dx;
    float y0f = floorf(fy), x0f = floorf(fx);
    float wy = fy - y0f, wx = fx - x0f;
    int iy0 = (int)y0f, ix0 = (int)x0f;
    int iy1 = iy0 + 1, ix1 = ix0 + 1;
    float vy0 = (iy0 >= 0 && iy0 < H_) ? 1.f : 0.f;
    float vy1 = (iy1 >= 0 && iy1 < H_) ? 1.f : 0.f;
    float vx0 = (ix0 >= 0 && ix0 < W_) ? 1.f : 0.f;
    float vx1 = (ix1 >= 0 && ix1 < W_) ? 1.f : 0.f;
    GeomT gm;
    gm.w00 = (1.f - wy) * (1.f - wx) * vy0 * vx0;
    gm.w01 = (1.f - wy) * wx * vy0 * vx1;
    gm.w10 = wy * (1.f - wx) * vy1 * vx0;
    gm.w11 = wy * wx * vy1 * vx1;
    int cy0 = min(max(iy0, 0), H_ - 1), cy1 = min(max(iy1, 0), H_ - 1);
    int cx0 = min(max(ix0, 0), W_ - 1), cx1 = min(max(ix1, 0), W_ - 1);
    int ch = half * 32 + cq * 8;
    gm.o00 = (cy0 * W_ + cx0) * 64 + ch;
    gm.o01 = (cy0 * W_ + cx1) * 64 + ch;
    gm.o10 = (cy1 * W_ + cx0) * 64 + ch;
    gm.o11 = (cy1 * W_ + cx1) * 64 + ch;
    gm.base = xtb + (size_t)g * HWsz * 64;
    return gm;
}

__device__ __forceinline__ void load_corners(const GeomT& g0, const GeomT& g1,
                                             u16x8 (&C)[8]) {
    C[0] = *(const u16x8*)(g0.base + g0.o00);
    C[1] = *(const u16x8*)(g0.base + g0.o01);
    C[2] = *(const u16x8*)(g0.base + g0.o10);
    C[3] = *(const u16x8*)(g0.base + g0.o11);
    C[4] = *(const u16x8*)(g1.base + g1.o00);
    C[5] = *(const u16x8*)(g1.base + g1.o01);
    C[6] = *(const u16x8*)(g1.base + g1.o10);
    C[7] = *(const u16x8*)(g1.base + g1.o11);
}

__device__ __forceinline__ s16x8 combine4(const u16x8& c00, const u16x8& c01,
                                          const u16x8& c10, const u16x8& c11,
                                          float w00, float w01, float w10, float w11) {
    s16x8 a;
    #pragma unroll
    for (int j = 0; j < 8; ++j) {
        float v = fmaf(w00, bf2f(c00[j]), fmaf(w01, bf2f(c01[j]),
                  fmaf(w10, bf2f(c10[j]), w11 * bf2f(c11[j]))));
        a[j] = (short)f2bf(v);
    }
    return a;
}

__device__ __forceinline__ void load_bfrag(const unsigned short* w2c, s16x8 (&B)[8]) {
    #pragma unroll
    for (int t = 0; t < 8; ++t) B[t] = *(const s16x8*)(w2c + t * 512);
}

__device__ __forceinline__ void mfma8(const s16x8& a, const s16x8 (&B)[8],
                                      f32x4 (&acc)[8]) {
    #pragma unroll
    for (int t = 0; t < 8; ++t)
        acc[t] = __builtin_amdgcn_mfma_f32_16x16x32_bf16(a, B[t], acc[t], 0, 0, 0);
}

// ---------------- main kernel (tier 2): depth-2 pipeline ----------------

__global__ __launch_bounds__(128, 2) void deform32_kernel(
    const unsigned short* __restrict__ xt, const float* __restrict__ b_off,
    const unsigned short* __restrict__ w2, float* __restrict__ out)
{
    __shared__ float off_lds[2][72 * 32];   // 18.4 KB

    const int tid  = threadIdx.x;
    const int lane = tid & 63;
    const int wv   = tid >> 6;
    // XCD swizzle: 1024 = 8 * 128 -> each XCD gets a contiguous 16-row band
    const int bid  = ((blockIdx.x & 7) << 7) | (blockIdx.x >> 3);
    const int nh   = wv;                    // oc base = nh*128
    const int xq   = bid & 7;
    const int h    = (bid >> 3) & 63;
    const int b    = bid >> 9;
    const int p16  = lane & 15;
    const int cq   = lane >> 4;
    const int wbase = xq * 32;

    const unsigned short* xtb = xt + (size_t)b * 4 * HWsz * 64;

    // ---- Phase A: offsets via MFMA, two 16-px groups (per wave) ----
    for (int pg = 0; pg < 2; ++pg) {
        f32x4 oa[5];
        #pragma unroll
        for (int t = 0; t < 5; ++t) {
            int o = t * 16 + p16;
            float bv = (o < 72) ? b_off[o] : 0.f;
            oa[t][0] = bv; oa[t][1] = bv; oa[t][2] = bv; oa[t][3] = bv;
        }
        const int pixg = h * W_ + wbase + pg * 16;
        #pragma unroll
        for (int c8 = 0; c8 < 8; ++c8) {
            const unsigned short* ap = xtb + (size_t)(c8 >> 1) * HWsz * 64
                                     + (size_t)(pixg + p16) * 64 + (c8 & 1) * 32 + cq * 8;
            s16x8 a = *(const s16x8*)ap;
            const unsigned short* wb = w2 + WMAIN_ELEMS + (size_t)(c8 * 5) * 512;
            #pragma unroll
            for (int t = 0; t < 5; ++t) {
                s16x8 bf = *(const s16x8*)(wb + t * 512 + lane * 8);
                oa[t] = __builtin_amdgcn_mfma_f32_16x16x32_bf16(a, bf, oa[t], 0, 0, 0);
            }
        }
        #pragma unroll
        for (int t = 0; t < 5; ++t) {
            int o = t * 16 + p16;
            if (o < 72) {
                #pragma unroll
                for (int r = 0; r < 4; ++r)
                    off_lds[wv][o * 32 + pg * 16 + cq * 4 + r] = oa[t][r];
            }
        }
    }
    // same-wave LDS RAW only (waves independent) -> compiler lgkmcnt.

    // ---- Phase B: 72 chunks, corners prefetched 2 ahead, wf loaded in-chunk ----
    f32x4 accP[8], accQ[8];
    #pragma unroll
    for (int t = 0; t < 8; ++t) {
        accP[t][0]=0;accP[t][1]=0;accP[t][2]=0;accP[t][3]=0;
        accQ[t][0]=0;accQ[t][1]=0;accQ[t][2]=0;accQ[t][3]=0;
    }

    const float* offp = &off_lds[wv][0];
    const int xc0 = wbase + p16, xc1 = wbase + 16 + p16;
    const unsigned short* w2m = w2 + nh * 4096 + lane * 8;

    // prologue: corners for chunks 0 (A set) and 1 (B set)
    GeomT gA0 = make_geomT(0, offp, h, xc0, p16, cq, xtb);
    GeomT gA1 = make_geomT(0, offp, h, xc1, 16 + p16, cq, xtb);
    u16x8 crA[8];
    load_corners(gA0, gA1, crA);
    GeomT gB0 = make_geomT(1, offp, h, xc0, p16, cq, xtb);
    GeomT gB1 = make_geomT(1, offp, h, xc1, 16 + p16, cq, xtb);
    u16x8 crB[8];
    load_corners(gB0, gB1, crB);

    for (int i = 0; i < 72; i += 2) {
        // ---- chunk i (A buffers) ----
        {
            s16x8 a0 = combine4(crA[0], crA[1], crA[2], crA[3],
                                gA0.w00, gA0.w01, gA0.w10, gA0.w11);
            s16x8 a1 = combine4(crA[4], crA[5], crA[6], crA[7],
                                gA1.w00, gA1.w01, gA1.w10, gA1.w11);
            __builtin_amdgcn_sched_barrier(0);
            s16x8 wf[8];
            load_bfrag(w2m + (size_t)i * 8192, wf);
            __builtin_amdgcn_sched_barrier(0);
            const int gn = (i + 2 < 72) ? i + 2 : i;       // tail: redundant
            gA0 = make_geomT(gn, offp, h, xc0, p16, cq, xtb);
            gA1 = make_geomT(gn, offp, h, xc1, 16 + p16, cq, xtb);
            load_corners(gA0, gA1, crA);
            __builtin_amdgcn_sched_barrier(0);
            mfma8(a0, wf, accP);      // waits wf only; crA prefetch stays in flight
            mfma8(a1, wf, accQ);
        }
        // ---- chunk i+1 (B buffers) ----
        {
            s16x8 a0 = combine4(crB[0], crB[1], crB[2], crB[3],
                                gB0.w00, gB0.w01, gB0.w10, gB0.w11);
            s16x8 a1 = combine4(crB[4], crB[5], crB[6], crB[7],
                                gB1.w00, gB1.w01, gB1.w10, gB1.w11);
            __builtin_amdgcn_sched_barrier(0);
            s16x8 wf[8];
            load_bfrag(w2m + (size_t)(i + 1) * 8192, wf);
            __builtin_amdgcn_sched_barrier(0);
            const int gn = (i + 3 < 72) ? i + 3 : i + 1;   // tail: redundant
            gB0 = make_geomT(gn, offp, h, xc0, p16, cq, xtb);
            gB1 = make_geomT(gn, offp, h, xc1, 16 + p16, cq, xtb);
            load_corners(gB0, gB1, crB);
            __builtin_amdgcn_sched_barrier(0);
            mfma8(a0, wf, accP);
            mfma8(a1, wf, accQ);
        }
    }

    // ---- epilogue: ReLU + float4 stores ----
    const size_t obase = (size_t)b * OC_ * HWsz + (size_t)h * W_ + wbase + cq * 4;
    #pragma unroll
    for (int t = 0; t < 8; ++t) {
        int oc = nh * 128 + t * 16 + p16;
        float4 r0, r1;
        r0.x = fmaxf(accP[t][0], 0.f); r0.y = fmaxf(accP[t][1], 0.f);
        r0.z = fmaxf(accP[t][2], 0.f); r0.w = fmaxf(accP[t][3], 0.f);
        r1.x = fmaxf(accQ[t][0], 0.f); r1.y = fmaxf(accQ[t][1], 0.f);
        r1.z = fmaxf(accQ[t][2], 0.f); r1.w = fmaxf(accQ[t][3], 0.f);
        *(float4*)(out + obase + (size_t)oc * HWsz) = r0;
        *(float4*)(out + obase + (size_t)oc * HWsz + 16) = r1;
    }
}

// ---------------- tier-1/0 fallback (v5 kernel, verified) ----------------

struct Geom {
    float w00, w01, w10, w11;
    int o00, o01, o10, o11;
    const float* base;
};

__device__ __forceinline__ Geom make_geom(
    int gkh, const float* offp, int h, int wbase, int p, int cq,
    const float* xA, const float* xB, const float* xC)
{
    const int half = gkh & 1, gk = gkh >> 1;
    const int k = gk % 9, g = gk / 9;
    const int ky = k / 3, kx = k % 3;
    float dy = offp[(2 * gk) * 16 + p];
    float dx = offp[(2 * gk + 1) * 16 + p];
    float fy = (float)(h - 1 + ky) + dy;
    float fx = (float)(wbase + p - 1 + kx) + dx;
    float y0f = floorf(fy), x0f = floorf(fx);
    float wy = fy - y0f, wx = fx - x0f;
    int iy0 = (int)y0f, ix0 = (int)x0f;
    int iy1 = iy0 + 1, ix1 = ix0 + 1;
    float vy0 = (iy0 >= 0 && iy0 < H_) ? 1.f : 0.f;
    float vy1 = (iy1 >= 0 && iy1 < H_) ? 1.f : 0.f;
    float vx0 = (ix0 >= 0 && ix0 < W_) ? 1.f : 0.f;
    float vx1 = (ix1 >= 0 && ix1 < W_) ? 1.f : 0.f;
    Geom gm;
    gm.w00 = (1.f - wy) * (1.f - wx) * vy0 * vx0;
    gm.w01 = (1.f - wy) * wx * vy0 * vx1;
    gm.w10 = wy * (1.f - wx) * vy1 * vx0;
    gm.w11 = wy * wx * vy1 * vx1;
    int cy0 = min(max(iy0, 0), H_ - 1), cy1 = min(max(iy1, 0), H_ - 1);
    int cx0 = min(max(ix0, 0), W_ - 1), cx1 = min(max(ix1, 0), W_ - 1);
    int choff = (half * 32 + cq * 8) * HWsz;
    gm.o00 = choff + cy0 * W_ + cx0;
    gm.o01 = choff + cy0 * W_ + cx1;
    gm.o10 = choff + cy1 * W_ + cx0;
    gm.o11 = choff + cy1 * W_ + cx1;
    gm.base = (g == 0) ? xA : (g == 1) ? xB : (g == 2) ? xC : xC + (size_t)64 * HWsz;
    return gm;
}

#define GATHER(J, Cv) do { \
    Cv.x = gm.base[gm.o00 + (J) * HWsz]; \
    Cv.y = gm.base[gm.o01 + (J) * HWsz]; \
    Cv.z = gm.base[gm.o10 + (J) * HWsz]; \
    Cv.w = gm.base[gm.o11 + (J) * HWsz]; \
} while (0)

#define COMB(Cv, IDX) \
    a[IDX] = (short)f2bf(fmaf(w00c, Cv.x, fmaf(w01c, Cv.y, fmaf(w10c, Cv.z, w11c * Cv.w))))

template<bool USE_WS>
__global__ __launch_bounds__(128, 3) void deform_kernel(
    const float* __restrict__ x0, const float* __restrict__ x1,
    const float* __restrict__ x2,
    const float* __restrict__ w_off, const float* __restrict__ b_off,
    const float* __restrict__ w_def, const unsigned short* __restrict__ w2,
    float* __restrict__ out)
{
    __shared__ float off_lds[2][72 * 16];

    const int tid  = threadIdx.x;
    const int lane = tid & 63;
    const int wv   = tid >> 6;
    const int bid  = ((blockIdx.x & 7) << 8) | (blockIdx.x >> 3);
    const int nh   = wv;
    const int ws_  = bid & 15;
    const int h    = (bid >> 4) & 63;
    const int b    = bid >> 10;
    const int p    = lane & 15;
    const int cq   = lane >> 4;
    const int wbase = ws_ * 16;
    const int pix  = h * W_ + wbase;

    const float* xA = x0 + (size_t)b * 64  * HWsz;
    const float* xB = x1 + (size_t)b * 64  * HWsz;
    const float* xC = x2 + (size_t)b * 128 * HWsz;

    f32x4 oa[5];
    #pragma unroll
    for (int t = 0; t < 5; ++t) {
        int o = t * 16 + p;
        float bv = (o < 72) ? b_off[o] : 0.f;
        oa[t][0] = bv; oa[t][1] = bv; oa[t][2] = bv; oa[t][3] = bv;
    }
    #pragma unroll
    for (int c8 = 0; c8 < 8; ++c8) {
        const float* src = (c8 < 2) ? xA + (size_t)c8 * 32 * HWsz
                         : (c8 < 4) ? xB + (size_t)(c8 - 2) * 32 * HWsz
                                    : xC + (size_t)(c8 - 4) * 32 * HWsz;
        s16x8 a;
        #pragma unroll
        for (int j = 0; j < 8; ++j)
            a[j] = (short)f2bf(src[(cq * 8 + j) * HWsz + pix + p]);
        #pragma unroll
        for (int t = 0; t < 5; ++t) {
            int o = t * 16 + p;
            s16x8 bf;
            if (USE_WS) {
                bf = *(const s16x8*)(w2 + WMAIN_ELEMS + (size_t)(c8 * 5 + t) * 512 + lane * 8);
            } else {
                #pragma unroll
                for (int j = 0; j < 8; ++j)
                    bf[j] = (o < 72) ? (short)f2bf(w_off[o * 256 + c8 * 32 + cq * 8 + j])
                                     : (short)0;
            }
            oa[t] = __builtin_amdgcn_mfma_f32_16x16x32_bf16(a, bf, oa[t], 0, 0, 0);
        }
    }
    #pragma unroll
    for (int t = 0; t < 5; ++t) {
        int o = t * 16 + p;
        if (o < 72) {
            #pragma unroll
            for (int r = 0; r < 4; ++r)
                off_lds[wv][o * 16 + cq * 4 + r] = oa[t][r];
        }
    }

    f32x4 acc0={0,0,0,0},acc1={0,0,0,0},acc2={0,0,0,0},acc3={0,0,0,0};
    f32x4 acc4={0,0,0,0},acc5={0,0,0,0},acc6={0,0,0,0},acc7={0,0,0,0};
    const float* offp = &off_lds[wv][0];

    for (int gkh = 0; gkh < 72; ++gkh) {
        Geom gm = make_geom(gkh, offp, h, wbase, p, cq, xA, xB, xC);
        float4 c0, c1, c2, c3, c4, c5, c6, c7;
        GATHER(0, c0); GATHER(1, c1); GATHER(2, c2); GATHER(3, c3);
        GATHER(4, c4); GATHER(5, c5); GATHER(6, c6); GATHER(7, c7);
        float w00c = gm.w00, w01c = gm.w01, w10c = gm.w10, w11c = gm.w11;
        s16x8 a;
        COMB(c0, 0); COMB(c1, 1); COMB(c2, 2); COMB(c3, 3);
        COMB(c4, 4); COMB(c5, 5); COMB(c6, 6); COMB(c7, 7);
        const int half = gkh & 1, gk = gkh >> 1;
        const int k = gk % 9, g = gk / 9;
        const int cbase = g * 64 + half * 32 + cq * 8;
        f32x4* accp[8] = {&acc0,&acc1,&acc2,&acc3,&acc4,&acc5,&acc6,&acc7};
        #pragma unroll
        for (int t = 0; t < 8; ++t) {
            int oc = nh * 128 + t * 16 + p;
            s16x8 bf;
            if (USE_WS) {
                bf = *(const s16x8*)(w2 + gkh * 8192 + nh * 4096 + t * 512 + lane * 8);
            } else {
                #pragma unroll
                for (int j = 0; j < 8; ++j)
                    bf[j] = (short)f2bf(w_def[(size_t)oc * 2304 + (size_t)(cbase + j) * 9 + k]);
            }
            *accp[t] = __builtin_amdgcn_mfma_f32_16x16x32_bf16(a, bf, *accp[t], 0, 0, 0);
        }
    }

    const size_t obase = (size_t)b * OC_ * HWsz + (size_t)h * W_ + wbase + cq * 4;
    f32x4 accs[8] = {acc0, acc1, acc2, acc3, acc4, acc5, acc6, acc7};
    #pragma unroll
    for (int t = 0; t < 8; ++t) {
        int oc = nh * 128 + t * 16 + p;
        float4 r;
        r.x = fmaxf(accs[t][0], 0.f);
        r.y = fmaxf(accs[t][1], 0.f);
        r.z = fmaxf(accs[t][2], 0.f);
        r.w = fmaxf(accs[t][3], 0.f);
        *(float4*)(out + obase + (size_t)oc * HWsz) = r;
    }
}

extern "C" void kernel_launch(void* const* d_in, const int* in_sizes, int n_in,
                              void* d_out, int out_size, void* d_ws, size_t ws_size,
                              hipStream_t stream) {
    const float* x0    = (const float*)d_in[0];
    const float* x1    = (const float*)d_in[1];
    const float* x2    = (const float*)d_in[2];
    const float* w_off = (const float*)d_in[3];
    const float* b_off = (const float*)d_in[4];
    const float* w_def = (const float*)d_in[5];
    float* out = (float*)d_out;

    const size_t w2_bytes   = (size_t)(WMAIN_ELEMS + WOFFB_ELEMS) * 2;
    const size_t full_bytes = (XT_ELEMS + WMAIN_ELEMS + WOFFB_ELEMS) * 2;   // ~18 MB

    if (ws_size >= full_bytes) {
        unsigned short* xt = (unsigned short*)d_ws;
        unsigned short* w2 = xt + XT_ELEMS;
        hipLaunchKernelGGL(xprep_kernel, dim3(512), dim3(256), 0, stream, x0, x1, x2, xt);
        hipLaunchKernelGGL(wprep_kernel, dim3((WMAIN_ELEMS + WOFFB_ELEMS) / 256), dim3(256),
                           0, stream, w_def, w_off, w2);
        hipLaunchKernelGGL(deform32_kernel, dim3(1024), dim3(128), 0, stream,
                           xt, b_off, w2, out);
    } else if (ws_size >= w2_bytes) {
        unsigned short* w2 = (unsigned short*)d_ws;
        hipLaunchKernelGGL(wprep_kernel, dim3((WMAIN_ELEMS + WOFFB_ELEMS) / 256), dim3(256),
                           0, stream, w_def, w_off, w2);
        hipLaunchKernelGGL((deform_kernel<true>), dim3(2048), dim3(128), 0, stream,
                           x0, x1, x2, w_off, b_off, w_def, w2, out);
    } else {
        hipLaunchKernelGGL((deform_kernel<false>), dim3(2048), dim3(128), 0, stream,
                           x0, x1, x2, w_off, b_off, w_def, (const unsigned short*)nullptr, out);
    }
}

// Round 9
// 113.192 us; speedup vs baseline: 7.7866x; 1.6266x over previous
//
#include <hip/hip_runtime.h>

// Deformable conv fusion v9: cooperative 8-wave block, shared gather + LDS-staged B.
// - 512 blocks x 512 thr; block = 64px x 256oc; exactly 2 blocks/CU, 4 waves/SIMD.
// - Gather: each wave 8px x 32ch (4ch/lane), done ONCE per pixel (no nh dup),
//   written to samp LDS (stride-40 rows). B chunk (16KB contiguous in w2)
//   staged via global_load_lds, double-buffered. 1 barrier/chunk.
// - Consumer: wave (nh,pg) = 16px x 128oc: ds_read A-frag + 8 B-frags + 8 MFMA.
// - VGPR capped 128 by __launch_bounds__(512,4). Spill tripwire: WRITE_SIZE.

constexpr int H_ = 64, W_ = 256;
constexpr int HWsz = H_ * W_;
constexpr int OC_ = 256;
constexpr int WMAIN_ELEMS = 72 * 16 * 64 * 8;
constexpr int WOFFB_ELEMS = 8 * 5 * 64 * 8;
constexpr size_t XT_ELEMS = (size_t)8 * HWsz * 64;   // [bg 8][y][x][c 64] bf16

using f32x4 = __attribute__((ext_vector_type(4))) float;
using s16x8 = __attribute__((ext_vector_type(8))) short;
using u16x8 = __attribute__((ext_vector_type(8))) unsigned short;
using u16x4 = __attribute__((ext_vector_type(4))) unsigned short;

__device__ __forceinline__ unsigned short f2bf(float f) {
    unsigned u = __float_as_uint(f);
    return (unsigned short)((u + 0x7fffu + ((u >> 16) & 1u)) >> 16);
}
__device__ __forceinline__ float bf2f(unsigned short u) {
    return __uint_as_float((unsigned)u << 16);
}
__device__ __forceinline__ void gload_lds16(const void* g, void* l) {
    __builtin_amdgcn_global_load_lds(
        (const __attribute__((address_space(1))) void*)g,
        (__attribute__((address_space(3))) void*)l, 16, 0, 0);
}

// ---------------- prep kernels (unchanged, verified) ----------------

__global__ __launch_bounds__(256) void wprep_kernel(const float* __restrict__ w_def,
                                                    const float* __restrict__ w_off,
                                                    unsigned short* __restrict__ w2) {
    int i = blockIdx.x * 256 + threadIdx.x;
    if (i < WMAIN_ELEMS) {
        int j = i & 7, lane = (i >> 3) & 63, t = (i >> 9) & 15, gkh = i >> 13;
        int half = gkh & 1, gk = gkh >> 1;
        int k = gk % 9, g = gk / 9;
        int oc = t * 16 + (lane & 15);
        int cin = g * 64 + half * 32 + (lane >> 4) * 8 + j;
        w2[i] = f2bf(w_def[(size_t)oc * 2304 + (size_t)cin * 9 + k]);
    } else if (i < WMAIN_ELEMS + WOFFB_ELEMS) {
        int i2 = i - WMAIN_ELEMS;
        int j = i2 & 7, lane = (i2 >> 3) & 63, idx = i2 >> 9;   // idx = c8*5 + t
        int t = idx % 5, c8 = idx / 5;
        int o = t * 16 + (lane & 15);
        int ch = c8 * 32 + (lane >> 4) * 8 + j;
        float v = (o < 72) ? w_off[o * 256 + ch] : 0.f;
        w2[i] = f2bf(v);
    }
}

__global__ __launch_bounds__(256) void xprep_kernel(const float* __restrict__ x0,
                                                    const float* __restrict__ x1,
                                                    const float* __restrict__ x2,
                                                    unsigned short* __restrict__ xt) {
    __shared__ unsigned short tl[256][66];
    const int bg = blockIdx.x >> 6;
    const int y  = blockIdx.x & 63;
    const int b  = bg >> 2, g = bg & 3;
    const int tid = threadIdx.x;
    const float* src = (g == 0) ? x0 + (size_t)b * 64 * HWsz
                     : (g == 1) ? x1 + (size_t)b * 64 * HWsz
                     : x2 + (size_t)b * 128 * HWsz + (size_t)(g - 2) * 64 * HWsz;
    src += y * W_;
    for (int c = 0; c < 64; ++c)
        tl[tid][c] = f2bf(src[(size_t)c * HWsz + tid]);
    __syncthreads();
    unsigned short* dst = xt + ((size_t)bg * HWsz + y * W_) * 64;
    #pragma unroll
    for (int s = 0; s < 8; ++s) {
        int si = s * 256 + tid;
        int px = si >> 3, q = si & 7;
        u16x8 v;
        #pragma unroll
        for (int j = 0; j < 8; ++j) v[j] = tl[px][q * 8 + j];
        *(u16x8*)(dst + (size_t)px * 64 + q * 8) = v;
    }
}

// ---------------- main kernel (tier 2): cooperative 8-wave ----------------

struct GPre {
    float w00, w01, w10, w11;
    u16x4 c00, c01, c10, c11;
};

__global__ __launch_bounds__(512, 4) void deform64_kernel(
    const unsigned short* __restrict__ xt, const float* __restrict__ b_off,
    const unsigned short* __restrict__ w2, float* __restrict__ out)
{
    __shared__ float off_lds[72 * 64];                     // 18432 B
    __shared__ __align__(16) unsigned short Bbuf[2][8192]; // 2 x 16 KB
    __shared__ __align__(16) unsigned short sbuf[2][2560]; // 2 x 5 KB ([64px][40])

    const int tid  = threadIdx.x;
    const int lane = tid & 63;
    const int wv   = tid >> 6;              // 0..7
    // XCD swizzle: 512 = 8 * 64 (bijective)
    const int bid  = ((blockIdx.x & 7) << 6) | (blockIdx.x >> 3);
    const int xt4  = bid & 3;               // 64-px x tile
    const int h    = (bid >> 2) & 63;
    const int b    = bid >> 8;
    const int xbase = xt4 * 64;
    // consumer role: wave = (nh, pg)
    const int nh   = wv & 1;
    const int pg   = wv >> 1;               // 0..3 (16 px each)
    const int p16  = lane & 15;
    const int cq   = lane >> 4;
    // gather role: 8 px/wave, 4 ch/lane
    const int bp   = wv * 8 + (lane >> 3);  // block-pixel 0..63
    const int chg  = lane & 7;              // ch-slot (4 ch)

    const unsigned short* xtb = xt + (size_t)b * 4 * HWsz * 64;

    // ---- Phase A: offsets via MFMA, waves 0-3 (pg_a = wv) ----
    if (wv < 4) {
        f32x4 oa[5];
        #pragma unroll
        for (int t = 0; t < 5; ++t) {
            int o = t * 16 + p16;
            float bv = (o < 72) ? b_off[o] : 0.f;
            oa[t][0] = bv; oa[t][1] = bv; oa[t][2] = bv; oa[t][3] = bv;
        }
        const int pixg = h * W_ + xbase + wv * 16;
        #pragma unroll
        for (int c8 = 0; c8 < 8; ++c8) {
            const unsigned short* ap = xtb + (size_t)(c8 >> 1) * HWsz * 64
                                     + (size_t)(pixg + p16) * 64 + (c8 & 1) * 32 + cq * 8;
            s16x8 a = *(const s16x8*)ap;
            const unsigned short* wb = w2 + WMAIN_ELEMS + (size_t)(c8 * 5) * 512;
            #pragma unroll
            for (int t = 0; t < 5; ++t) {
                s16x8 bf = *(const s16x8*)(wb + t * 512 + lane * 8);
                oa[t] = __builtin_amdgcn_mfma_f32_16x16x32_bf16(a, bf, oa[t], 0, 0, 0);
            }
        }
        #pragma unroll
        for (int t = 0; t < 5; ++t) {
            int o = t * 16 + p16;
            if (o < 72) {
                #pragma unroll
                for (int r = 0; r < 4; ++r)
                    off_lds[o * 64 + wv * 16 + cq * 4 + r] = oa[t][r];
            }
        }
    }
    __syncthreads();

    // ---- helpers ----
    auto stageB = [&](int gkh, int bsel) {
        const char* src = (const char*)w2 + (size_t)gkh * 16384 + (size_t)tid * 16;
        char* dst = (char*)&Bbuf[bsel][0] + wv * 1024;   // wave-uniform base
        gload_lds16(src, dst);
        gload_lds16(src + 8192, dst + 8192);
    };
    auto gpre = [&](int gkh) -> GPre {
        const int half = gkh & 1, gk = gkh >> 1;
        const int k = gk % 9, g = gk / 9;
        const int ky = k / 3, kx = k % 3;
        float dy = off_lds[(2 * gk) * 64 + bp];
        float dx = off_lds[(2 * gk + 1) * 64 + bp];
        float fy = (float)(h - 1 + ky) + dy;
        float fx = (float)(xbase + bp - 1 + kx) + dx;
        float y0f = floorf(fy), x0f = floorf(fx);
        float wy = fy - y0f, wx = fx - x0f;
        int iy0 = (int)y0f, ix0 = (int)x0f;
        int iy1 = iy0 + 1, ix1 = ix0 + 1;
        float vy0 = (iy0 >= 0 && iy0 < H_) ? 1.f : 0.f;
        float vy1 = (iy1 >= 0 && iy1 < H_) ? 1.f : 0.f;
        float vx0 = (ix0 >= 0 && ix0 < W_) ? 1.f : 0.f;
        float vx1 = (ix1 >= 0 && ix1 < W_) ? 1.f : 0.f;
        GPre G;
        G.w00 = (1.f - wy) * (1.f - wx) * vy0 * vx0;
        G.w01 = (1.f - wy) * wx * vy0 * vx1;
        G.w10 = wy * (1.f - wx) * vy1 * vx0;
        G.w11 = wy * wx * vy1 * vx1;
        int cy0 = min(max(iy0, 0), H_ - 1), cy1 = min(max(iy1, 0), H_ - 1);
        int cx0 = min(max(ix0, 0), W_ - 1), cx1 = min(max(ix1, 0), W_ - 1);
        const int eb = half * 32 + chg * 4;
        const unsigned short* src = xtb + (size_t)g * HWsz * 64;
        G.c00 = *(const u16x4*)(src + (cy0 * W_ + cx0) * 64 + eb);
        G.c01 = *(const u16x4*)(src + (cy0 * W_ + cx1) * 64 + eb);
        G.c10 = *(const u16x4*)(src + (cy1 * W_ + cx0) * 64 + eb);
        G.c11 = *(const u16x4*)(src + (cy1 * W_ + cx1) * 64 + eb);
        return G;
    };
    auto gpost = [&](const GPre& G, int bsel) {
        u16x4 res;
        #pragma unroll
        for (int j = 0; j < 4; ++j) {
            float v = fmaf(G.w00, bf2f(G.c00[j]), fmaf(G.w01, bf2f(G.c01[j]),
                      fmaf(G.w10, bf2f(G.c10[j]), G.w11 * bf2f(G.c11[j]))));
            res[j] = f2bf(v);
        }
        *(u16x4*)&sbuf[bsel][bp * 40 + chg * 4] = res;
    };

    // ---- Phase B: 72 chunks, 1 barrier/chunk ----
    f32x4 acc[8];
    #pragma unroll
    for (int t = 0; t < 8; ++t) { acc[t][0]=0; acc[t][1]=0; acc[t][2]=0; acc[t][3]=0; }

    // prologue: chunk 0
    stageB(0, 0);
    {
        GPre G0 = gpre(0);
        gpost(G0, 0);
    }
    __syncthreads();

    const int arow = (pg * 16 + p16) * 40 + cq * 8;
    const unsigned short* bbase0 = &Bbuf[0][0] + (nh * 8) * 512 + lane * 8;
    const unsigned short* bbase1 = &Bbuf[1][0] + (nh * 8) * 512 + lane * 8;

    for (int i = 0; i < 72; ++i) {
        const int cur = i & 1;
        GPre G;
        const bool pf = (i < 71);
        if (pf) {
            stageB(i + 1, cur ^ 1);
            G = gpre(i + 1);
        }
        __builtin_amdgcn_sched_barrier(0);
        // consume chunk i
        s16x8 a = *(const s16x8*)&sbuf[cur][arow];
        const unsigned short* bb = cur ? bbase1 : bbase0;
        #pragma unroll
        for (int t = 0; t < 8; ++t) {
            s16x8 bf = *(const s16x8*)(bb + t * 512);
            acc[t] = __builtin_amdgcn_mfma_f32_16x16x32_bf16(a, bf, acc[t], 0, 0, 0);
        }
        __builtin_amdgcn_sched_barrier(0);
        if (pf) gpost(G, cur ^ 1);
        __syncthreads();
    }

    // ---- epilogue: ReLU + float4 stores ----
    // D: row(px within 16) = cq*4 + r, col(oc) = t*16 + p16
    const size_t obase = (size_t)b * OC_ * HWsz + (size_t)h * W_
                       + xbase + pg * 16 + cq * 4;
    #pragma unroll
    for (int t = 0; t < 8; ++t) {
        int oc = nh * 128 + t * 16 + p16;
        float4 r;
        r.x = fmaxf(acc[t][0], 0.f);
        r.y = fmaxf(acc[t][1], 0.f);
        r.z = fmaxf(acc[t][2], 0.f);
        r.w = fmaxf(acc[t][3], 0.f);
        *(float4*)(out + obase + (size_t)oc * HWsz) = r;
    }
}

// ---------------- tier-1/0 fallback (v5 kernel, verified) ----------------

struct Geom {
    float w00, w01, w10, w11;
    int o00, o01, o10, o11;
    const float* base;
};

__device__ __forceinline__ Geom make_geom(
    int gkh, const float* offp, int h, int wbase, int p, int cq,
    const float* xA, const float* xB, const float* xC)
{
    const int half = gkh & 1, gk = gkh >> 1;
    const int k = gk % 9, g = gk / 9;
    const int ky = k / 3, kx = k % 3;
    float dy = offp[(2 * gk) * 16 + p];
    float dx = offp[(2 * gk + 1) * 16 + p];
    float fy = (float)(h - 1 + ky) + dy;
    float fx = (float)(wbase + p - 1 + kx) + dx;
    float y0f = floorf(fy), x0f = floorf(fx);
    float wy = fy - y0f, wx = fx - x0f;
    int iy0 = (int)y0f, ix0 = (int)x0f;
    int iy1 = iy0 + 1, ix1 = ix0 + 1;
    float vy0 = (iy0 >= 0 && iy0 < H_) ? 1.f : 0.f;
    float vy1 = (iy1 >= 0 && iy1 < H_) ? 1.f : 0.f;
    float vx0 = (ix0 >= 0 && ix0 < W_) ? 1.f : 0.f;
    float vx1 = (ix1 >= 0 && ix1 < W_) ? 1.f : 0.f;
    Geom gm;
    gm.w00 = (1.f - wy) * (1.f - wx) * vy0 * vx0;
    gm.w01 = (1.f - wy) * wx * vy0 * vx1;
    gm.w10 = wy * (1.f - wx) * vy1 * vx0;
    gm.w11 = wy * wx * vy1 * vx1;
    int cy0 = min(max(iy0, 0), H_ - 1), cy1 = min(max(iy1, 0), H_ - 1);
    int cx0 = min(max(ix0, 0), W_ - 1), cx1 = min(max(ix1, 0), W_ - 1);
    int choff = (half * 32 + cq * 8) * HWsz;
    gm.o00 = choff + cy0 * W_ + cx0;
    gm.o01 = choff + cy0 * W_ + cx1;
    gm.o10 = choff + cy1 * W_ + cx0;
    gm.o11 = choff + cy1 * W_ + cx1;
    gm.base = (g == 0) ? xA : (g == 1) ? xB : (g == 2) ? xC : xC + (size_t)64 * HWsz;
    return gm;
}

#define GATHER(J, Cv) do { \
    Cv.x = gm.base[gm.o00 + (J) * HWsz]; \
    Cv.y = gm.base[gm.o01 + (J) * HWsz]; \
    Cv.z = gm.base[gm.o10 + (J) * HWsz]; \
    Cv.w = gm.base[gm.o11 + (J) * HWsz]; \
} while (0)

#define COMB(Cv, IDX) \
    a[IDX] = (short)f2bf(fmaf(w00c, Cv.x, fmaf(w01c, Cv.y, fmaf(w10c, Cv.z, w11c * Cv.w))))

template<bool USE_WS>
__global__ __launch_bounds__(128, 3) void deform_kernel(
    const float* __restrict__ x0, const float* __restrict__ x1,
    const float* __restrict__ x2,
    const float* __restrict__ w_off, const float* __restrict__ b_off,
    const float* __restrict__ w_def, const unsigned short* __restrict__ w2,
    float* __restrict__ out)
{
    __shared__ float off_lds[2][72 * 16];

    const int tid  = threadIdx.x;
    const int lane = tid & 63;
    const int wv   = tid >> 6;
    const int bid  = ((blockIdx.x & 7) << 8) | (blockIdx.x >> 3);
    const int nh   = wv;
    const int ws_  = bid & 15;
    const int h    = (bid >> 4) & 63;
    const int b    = bid >> 10;
    const int p    = lane & 15;
    const int cq   = lane >> 4;
    const int wbase = ws_ * 16;
    const int pix  = h * W_ + wbase;

    const float* xA = x0 + (size_t)b * 64  * HWsz;
    const float* xB = x1 + (size_t)b * 64  * HWsz;
    const float* xC = x2 + (size_t)b * 128 * HWsz;

    f32x4 oa[5];
    #pragma unroll
    for (int t = 0; t < 5; ++t) {
        int o = t * 16 + p;
        float bv = (o < 72) ? b_off[o] : 0.f;
        oa[t][0] = bv; oa[t][1] = bv; oa[t][2] = bv; oa[t][3] = bv;
    }
    #pragma unroll
    for (int c8 = 0; c8 < 8; ++c8) {
        const float* src = (c8 < 2) ? xA + (size_t)c8 * 32 * HWsz
                         : (c8 < 4) ? xB + (size_t)(c8 - 2) * 32 * HWsz
                                    : xC + (size_t)(c8 - 4) * 32 * HWsz;
        s16x8 a;
        #pragma unroll
        for (int j = 0; j < 8; ++j)
            a[j] = (short)f2bf(src[(cq * 8 + j) * HWsz + pix + p]);
        #pragma unroll
        for (int t = 0; t < 5; ++t) {
            int o = t * 16 + p;
            s16x8 bf;
            if (USE_WS) {
                bf = *(const s16x8*)(w2 + WMAIN_ELEMS + (size_t)(c8 * 5 + t) * 512 + lane * 8);
            } else {
                #pragma unroll
                for (int j = 0; j < 8; ++j)
                    bf[j] = (o < 72) ? (short)f2bf(w_off[o * 256 + c8 * 32 + cq * 8 + j])
                                     : (short)0;
            }
            oa[t] = __builtin_amdgcn_mfma_f32_16x16x32_bf16(a, bf, oa[t], 0, 0, 0);
        }
    }
    #pragma unroll
    for (int t = 0; t < 5; ++t) {
        int o = t * 16 + p;
        if (o < 72) {
            #pragma unroll
            for (int r = 0; r < 4; ++r)
                off_lds[wv][o * 16 + cq * 4 + r] = oa[t][r];
        }
    }

    f32x4 acc0={0,0,0,0},acc1={0,0,0,0},acc2={0,0,0,0},acc3={0,0,0,0};
    f32x4 acc4={0,0,0,0},acc5={0,0,0,0},acc6={0,0,0,0},acc7={0,0,0,0};
    const float* offp = &off_lds[wv][0];

    for (int gkh = 0; gkh < 72; ++gkh) {
        Geom gm = make_geom(gkh, offp, h, wbase, p, cq, xA, xB, xC);
        float4 c0, c1, c2, c3, c4, c5, c6, c7;
        GATHER(0, c0); GATHER(1, c1); GATHER(2, c2); GATHER(3, c3);
        GATHER(4, c4); GATHER(5, c5); GATHER(6, c6); GATHER(7, c7);
        float w00c = gm.w00, w01c = gm.w01, w10c = gm.w10, w11c = gm.w11;
        s16x8 a;
        COMB(c0, 0); COMB(c1, 1); COMB(c2, 2); COMB(c3, 3);
        COMB(c4, 4); COMB(c5, 5); COMB(c6, 6); COMB(c7, 7);
        const int half = gkh & 1, gk = gkh >> 1;
        const int k = gk % 9, g = gk / 9;
        const int cbase = g * 64 + half * 32 + cq * 8;
        f32x4* accp[8] = {&acc0,&acc1,&acc2,&acc3,&acc4,&acc5,&acc6,&acc7};
        #pragma unroll
        for (int t = 0; t < 8; ++t) {
            int oc = nh * 128 + t * 16 + p;
            s16x8 bf;
            if (USE_WS) {
                bf = *(const s16x8*)(w2 + gkh * 8192 + nh * 4096 + t * 512 + lane * 8);
            } else {
                #pragma unroll
                for (int j = 0; j < 8; ++j)
                    bf[j] = (short)f2bf(w_def[(size_t)oc * 2304 + (size_t)(cbase + j) * 9 + k]);
            }
            *accp[t] = __builtin_amdgcn_mfma_f32_16x16x32_bf16(a, bf, *accp[t], 0, 0, 0);
        }
    }

    const size_t obase = (size_t)b * OC_ * HWsz + (size_t)h * W_ + wbase + cq * 4;
    f32x4 accs[8] = {acc0, acc1, acc2, acc3, acc4, acc5, acc6, acc7};
    #pragma unroll
    for (int t = 0; t < 8; ++t) {
        int oc = nh * 128 + t * 16 + p;
        float4 r;
        r.x = fmaxf(accs[t][0], 0.f);
        r.y = fmaxf(accs[t][1], 0.f);
        r.z = fmaxf(accs[t][2], 0.f);
        r.w = fmaxf(accs[t][3], 0.f);
        *(float4*)(out + obase + (size_t)oc * HWsz) = r;
    }
}

extern "C" void kernel_launch(void* const* d_in, const int* in_sizes, int n_in,
                              void* d_out, int out_size, void* d_ws, size_t ws_size,
                              hipStream_t stream) {
    const float* x0    = (const float*)d_in[0];
    const float* x1    = (const float*)d_in[1];
    const float* x2    = (const float*)d_in[2];
    const float* w_off = (const float*)d_in[3];
    const float* b_off = (const float*)d_in[4];
    const float* w_def = (const float*)d_in[5];
    float* out = (float*)d_out;

    const size_t w2_bytes   = (size_t)(WMAIN_ELEMS + WOFFB_ELEMS) * 2;
    const size_t full_bytes = (XT_ELEMS + WMAIN_ELEMS + WOFFB_ELEMS) * 2;   // ~18 MB

    if (ws_size >= full_bytes) {
        unsigned short* xt = (unsigned short*)d_ws;
        unsigned short* w2 = xt + XT_ELEMS;
        hipLaunchKernelGGL(xprep_kernel, dim3(512), dim3(256), 0, stream, x0, x1, x2, xt);
        hipLaunchKernelGGL(wprep_kernel, dim3((WMAIN_ELEMS + WOFFB_ELEMS) / 256), dim3(256),
                           0, stream, w_def, w_off, w2);
        hipLaunchKernelGGL(deform64_kernel, dim3(512), dim3(512), 0, stream,
                           xt, b_off, w2, out);
    } else if (ws_size >= w2_bytes) {
        unsigned short* w2 = (unsigned short*)d_ws;
        hipLaunchKernelGGL(wprep_kernel, dim3((WMAIN_ELEMS + WOFFB_ELEMS) / 256), dim3(256),
                           0, stream, w_def, w_off, w2);
        hipLaunchKernelGGL((deform_kernel<true>), dim3(2048), dim3(128), 0, stream,
                           x0, x1, x2, w_off, b_off, w_def, w2, out);
    } else {
        hipLaunchKernelGGL((deform_kernel<false>), dim3(2048), dim3(128), 0, stream,
                           x0, x1, x2, w_off, b_off, w_def, (const unsigned short*)nullptr, out);
    }
}

// Round 10
// 91.086 us; speedup vs baseline: 9.6763x; 1.2427x over previous
//
#include <hip/hip_runtime.h>

// Deformable conv fusion v10: v9 + gk-merged gather (64-ch double-chunks).
// - 512 blocks x 512 thr, 64px x 256oc, 2 blocks/CU, 4 waves/SIMD.
// - 36 double-chunks: ONE geometry per gk (halves share it), ONE u16x8 corner
//   load covers both 32-ch halves, barriers per channel halved.
// - cvt_pk_bf16_f32 packs combine output (2 vals/inst vs 4-inst f2bf).
// - sbuf XOR-swizzled: slot' = slot ^ cq ^ (half<<2) -> write <=2-way,
//   read stays full-cover permutation (conflict-free).
// - B single-buffered 32KB (both halves of one gk); 2 barriers/double-chunk.

constexpr int H_ = 64, W_ = 256;
constexpr int HWsz = H_ * W_;
constexpr int OC_ = 256;
constexpr int WMAIN_ELEMS = 72 * 16 * 64 * 8;
constexpr int WOFFB_ELEMS = 8 * 5 * 64 * 8;
constexpr size_t XT_ELEMS = (size_t)8 * HWsz * 64;   // [bg 8][y][x][c 64] bf16

using f32x4 = __attribute__((ext_vector_type(4))) float;
using s16x8 = __attribute__((ext_vector_type(8))) short;
using u16x8 = __attribute__((ext_vector_type(8))) unsigned short;

__device__ __forceinline__ unsigned short f2bf(float f) {
    unsigned u = __float_as_uint(f);
    return (unsigned short)((u + 0x7fffu + ((u >> 16) & 1u)) >> 16);
}
__device__ __forceinline__ float bf2f(unsigned short u) {
    return __uint_as_float((unsigned)u << 16);
}
__device__ __forceinline__ unsigned cvt_pk_bf16(float lo, float hi) {
    unsigned r;
    asm("v_cvt_pk_bf16_f32 %0, %1, %2" : "=v"(r) : "v"(lo), "v"(hi));
    return r;   // r[15:0]=bf16(lo), r[31:16]=bf16(hi)
}
__device__ __forceinline__ void gload_lds16(const void* g, void* l) {
    __builtin_amdgcn_global_load_lds(
        (const __attribute__((address_space(1))) void*)g,
        (__attribute__((address_space(3))) void*)l, 16, 0, 0);
}

// ---------------- prep kernels (unchanged, verified) ----------------

__global__ __launch_bounds__(256) void wprep_kernel(const float* __restrict__ w_def,
                                                    const float* __restrict__ w_off,
                                                    unsigned short* __restrict__ w2) {
    int i = blockIdx.x * 256 + threadIdx.x;
    if (i < WMAIN_ELEMS) {
        int j = i & 7, lane = (i >> 3) & 63, t = (i >> 9) & 15, gkh = i >> 13;
        int half = gkh & 1, gk = gkh >> 1;
        int k = gk % 9, g = gk / 9;
        int oc = t * 16 + (lane & 15);
        int cin = g * 64 + half * 32 + (lane >> 4) * 8 + j;
        w2[i] = f2bf(w_def[(size_t)oc * 2304 + (size_t)cin * 9 + k]);
    } else if (i < WMAIN_ELEMS + WOFFB_ELEMS) {
        int i2 = i - WMAIN_ELEMS;
        int j = i2 & 7, lane = (i2 >> 3) & 63, idx = i2 >> 9;   // idx = c8*5 + t
        int t = idx % 5, c8 = idx / 5;
        int o = t * 16 + (lane & 15);
        int ch = c8 * 32 + (lane >> 4) * 8 + j;
        float v = (o < 72) ? w_off[o * 256 + ch] : 0.f;
        w2[i] = f2bf(v);
    }
}

__global__ __launch_bounds__(256) void xprep_kernel(const float* __restrict__ x0,
                                                    const float* __restrict__ x1,
                                                    const float* __restrict__ x2,
                                                    unsigned short* __restrict__ xt) {
    __shared__ unsigned short tl[256][66];
    const int bg = blockIdx.x >> 6;
    const int y  = blockIdx.x & 63;
    const int b  = bg >> 2, g = bg & 3;
    const int tid = threadIdx.x;
    const float* src = (g == 0) ? x0 + (size_t)b * 64 * HWsz
                     : (g == 1) ? x1 + (size_t)b * 64 * HWsz
                     : x2 + (size_t)b * 128 * HWsz + (size_t)(g - 2) * 64 * HWsz;
    src += y * W_;
    for (int c = 0; c < 64; ++c)
        tl[tid][c] = f2bf(src[(size_t)c * HWsz + tid]);
    __syncthreads();
    unsigned short* dst = xt + ((size_t)bg * HWsz + y * W_) * 64;
    #pragma unroll
    for (int s = 0; s < 8; ++s) {
        int si = s * 256 + tid;
        int px = si >> 3, q = si & 7;
        u16x8 v;
        #pragma unroll
        for (int j = 0; j < 8; ++j) v[j] = tl[px][q * 8 + j];
        *(u16x8*)(dst + (size_t)px * 64 + q * 8) = v;
    }
}

// ---------------- main kernel (tier 2): gk-merged cooperative ----------------

struct GPre {
    float w00, w01, w10, w11;
    u16x8 c00, c01, c10, c11;   // 8 channels (both halves) x 4 corners
};

__global__ __launch_bounds__(512, 4) void deform64_kernel(
    const unsigned short* __restrict__ xt, const float* __restrict__ b_off,
    const unsigned short* __restrict__ w2, float* __restrict__ out)
{
    __shared__ float off_lds[72 * 64];                      // 18432 B
    __shared__ __align__(16) unsigned short Bbuf[16384];    // 32 KB (one gk, 2 halves)
    __shared__ __align__(16) unsigned short sbuf16[8192];   // 2 x 8 KB A-tiles

    const int tid  = threadIdx.x;
    const int lane = tid & 63;
    const int wv   = tid >> 6;              // 0..7
    // XCD swizzle: 512 = 8 * 64 (bijective)
    const int bid  = ((blockIdx.x & 7) << 6) | (blockIdx.x >> 3);
    const int xt4  = bid & 3;
    const int h    = (bid >> 2) & 63;
    const int b    = bid >> 8;
    const int xbase = xt4 * 64;
    // consumer role
    const int nh   = wv & 1;
    const int pg   = wv >> 1;               // 0..3
    const int p16  = lane & 15;
    const int cq   = lane >> 4;
    // gather role: 8 px/wave, 8 ch/lane (both halves)
    const int bp   = wv * 8 + (lane >> 3);  // block-pixel 0..63
    const int chg  = lane & 7;              // 8-ch slot
    const int halfw = chg >> 2;
    const int cqw   = chg & 3;
    const int slotw = ((cqw << 4) | (bp & 15)) ^ cqw ^ (halfw << 2);
    const int sbw   = halfw * 2048 + (bp >> 4) * 512 + slotw * 8;   // u16 units
    // consumer read offsets (swizzle-matched)
    const int roff0 = pg * 512 + (lane ^ cq) * 8;
    const int roff1 = 2048 + pg * 512 + (lane ^ cq ^ 4) * 8;

    const unsigned short* xtb = xt + (size_t)b * 4 * HWsz * 64;

    // ---- Phase A: offsets via MFMA, waves 0-3 ----
    if (wv < 4) {
        f32x4 oa[5];
        #pragma unroll
        for (int t = 0; t < 5; ++t) {
            int o = t * 16 + p16;
            float bv = (o < 72) ? b_off[o] : 0.f;
            oa[t][0] = bv; oa[t][1] = bv; oa[t][2] = bv; oa[t][3] = bv;
        }
        const int pixg = h * W_ + xbase + wv * 16;
        #pragma unroll
        for (int c8 = 0; c8 < 8; ++c8) {
            const unsigned short* ap = xtb + (size_t)(c8 >> 1) * HWsz * 64
                                     + (size_t)(pixg + p16) * 64 + (c8 & 1) * 32 + cq * 8;
            s16x8 a = *(const s16x8*)ap;
            const unsigned short* wb = w2 + WMAIN_ELEMS + (size_t)(c8 * 5) * 512;
            #pragma unroll
            for (int t = 0; t < 5; ++t) {
                s16x8 bf = *(const s16x8*)(wb + t * 512 + lane * 8);
                oa[t] = __builtin_amdgcn_mfma_f32_16x16x32_bf16(a, bf, oa[t], 0, 0, 0);
            }
        }
        #pragma unroll
        for (int t = 0; t < 5; ++t) {
            int o = t * 16 + p16;
            if (o < 72) {
                #pragma unroll
                for (int r = 0; r < 4; ++r)
                    off_lds[o * 64 + wv * 16 + cq * 4 + r] = oa[t][r];
            }
        }
    }
    __syncthreads();

    // ---- helpers ----
    auto stageB = [&](int gk) {
        const char* src = (const char*)w2 + (size_t)gk * 32768 + (size_t)tid * 16;
        char* dst = (char*)&Bbuf[0] + wv * 1024;
        #pragma unroll
        for (int q = 0; q < 4; ++q)
            gload_lds16(src + q * 8192, dst + q * 8192);
    };
    auto gpre = [&](int gk) -> GPre {
        const int k = gk % 9, g = gk / 9;
        const int ky = k / 3, kx = k % 3;
        float dy = off_lds[(2 * gk) * 64 + bp];
        float dx = off_lds[(2 * gk + 1) * 64 + bp];
        float fy = (float)(h - 1 + ky) + dy;
        float fx = (float)(xbase + bp - 1 + kx) + dx;
        float y0f = floorf(fy), x0f = floorf(fx);
        float wy = fy - y0f, wx = fx - x0f;
        int iy0 = (int)y0f, ix0 = (int)x0f;
        int iy1 = iy0 + 1, ix1 = ix0 + 1;
        float vy0 = (iy0 >= 0 && iy0 < H_) ? 1.f : 0.f;
        float vy1 = (iy1 >= 0 && iy1 < H_) ? 1.f : 0.f;
        float vx0 = (ix0 >= 0 && ix0 < W_) ? 1.f : 0.f;
        float vx1 = (ix1 >= 0 && ix1 < W_) ? 1.f : 0.f;
        GPre G;
        G.w00 = (1.f - wy) * (1.f - wx) * vy0 * vx0;
        G.w01 = (1.f - wy) * wx * vy0 * vx1;
        G.w10 = wy * (1.f - wx) * vy1 * vx0;
        G.w11 = wy * wx * vy1 * vx1;
        int cy0 = min(max(iy0, 0), H_ - 1), cy1 = min(max(iy1, 0), H_ - 1);
        int cx0 = min(max(ix0, 0), W_ - 1), cx1 = min(max(ix1, 0), W_ - 1);
        const unsigned short* src = xtb + (size_t)g * HWsz * 64 + chg * 8;
        G.c00 = *(const u16x8*)(src + (cy0 * W_ + cx0) * 64);
        G.c01 = *(const u16x8*)(src + (cy0 * W_ + cx1) * 64);
        G.c10 = *(const u16x8*)(src + (cy1 * W_ + cx0) * 64);
        G.c11 = *(const u16x8*)(src + (cy1 * W_ + cx1) * 64);
        return G;
    };
    auto gpost = [&](const GPre& G, int buf) {
        unsigned d[4];
        #pragma unroll
        for (int q = 0; q < 4; ++q) {
            float v0 = fmaf(G.w00, bf2f(G.c00[2*q]), fmaf(G.w01, bf2f(G.c01[2*q]),
                       fmaf(G.w10, bf2f(G.c10[2*q]), G.w11 * bf2f(G.c11[2*q]))));
            float v1 = fmaf(G.w00, bf2f(G.c00[2*q+1]), fmaf(G.w01, bf2f(G.c01[2*q+1]),
                       fmaf(G.w10, bf2f(G.c10[2*q+1]), G.w11 * bf2f(G.c11[2*q+1]))));
            d[q] = cvt_pk_bf16(v0, v1);
        }
        uint4 v4; v4.x = d[0]; v4.y = d[1]; v4.z = d[2]; v4.w = d[3];
        *(uint4*)&sbuf16[buf * 4096 + sbw] = v4;
    };

    // ---- Phase B: 36 double-chunks ----
    f32x4 acc[8];
    #pragma unroll
    for (int t = 0; t < 8; ++t) { acc[t][0]=0; acc[t][1]=0; acc[t][2]=0; acc[t][3]=0; }

    // prologue
    stageB(0);
    {
        GPre G0 = gpre(0);
        gpost(G0, 0);
    }
    GPre G = gpre(1);

    for (int i = 0; i < 36; ++i) {
        __syncthreads();   // (1) B[gk=i] staged + sbuf[i&1] written
        const int cur = i & 1;
        const unsigned short* sb = sbuf16 + cur * 4096;
        {   // half 0
            s16x8 a = *(const s16x8*)(sb + roff0);
            const unsigned short* bb = Bbuf + nh * 4096 + lane * 8;
            #pragma unroll
            for (int t = 0; t < 8; ++t) {
                s16x8 bf = *(const s16x8*)(bb + t * 512);
                acc[t] = __builtin_amdgcn_mfma_f32_16x16x32_bf16(a, bf, acc[t], 0, 0, 0);
            }
        }
        {   // half 1
            s16x8 a = *(const s16x8*)(sb + roff1);
            const unsigned short* bb = Bbuf + 8192 + nh * 4096 + lane * 8;
            #pragma unroll
            for (int t = 0; t < 8; ++t) {
                s16x8 bf = *(const s16x8*)(bb + t * 512);
                acc[t] = __builtin_amdgcn_mfma_f32_16x16x32_bf16(a, bf, acc[t], 0, 0, 0);
            }
        }
        if (i < 35) gpost(G, cur ^ 1);         // A(i+1) -> other sbuf
        __syncthreads();   // (2) all B[i] reads done -> safe to restage
        if (i < 35) stageB(i + 1);
        if (i < 34) G = gpre(i + 2);
    }

    // ---- epilogue: ReLU + float4 stores ----
    const size_t obase = (size_t)b * OC_ * HWsz + (size_t)h * W_
                       + xbase + pg * 16 + cq * 4;
    #pragma unroll
    for (int t = 0; t < 8; ++t) {
        int oc = nh * 128 + t * 16 + p16;
        float4 r;
        r.x = fmaxf(acc[t][0], 0.f);
        r.y = fmaxf(acc[t][1], 0.f);
        r.z = fmaxf(acc[t][2], 0.f);
        r.w = fmaxf(acc[t][3], 0.f);
        *(float4*)(out + obase + (size_t)oc * HWsz) = r;
    }
}

// ---------------- tier-1/0 fallback (v5 kernel, verified) ----------------

struct Geom {
    float w00, w01, w10, w11;
    int o00, o01, o10, o11;
    const float* base;
};

__device__ __forceinline__ Geom make_geom(
    int gkh, const float* offp, int h, int wbase, int p, int cq,
    const float* xA, const float* xB, const float* xC)
{
    const int half = gkh & 1, gk = gkh >> 1;
    const int k = gk % 9, g = gk / 9;
    const int ky = k / 3, kx = k % 3;
    float dy = offp[(2 * gk) * 16 + p];
    float dx = offp[(2 * gk + 1) * 16 + p];
    float fy = (float)(h - 1 + ky) + dy;
    float fx = (float)(wbase + p - 1 + kx) + dx;
    float y0f = floorf(fy), x0f = floorf(fx);
    float wy = fy - y0f, wx = fx - x0f;
    int iy0 = (int)y0f, ix0 = (int)x0f;
    int iy1 = iy0 + 1, ix1 = ix0 + 1;
    float vy0 = (iy0 >= 0 && iy0 < H_) ? 1.f : 0.f;
    float vy1 = (iy1 >= 0 && iy1 < H_) ? 1.f : 0.f;
    float vx0 = (ix0 >= 0 && ix0 < W_) ? 1.f : 0.f;
    float vx1 = (ix1 >= 0 && ix1 < W_) ? 1.f : 0.f;
    Geom gm;
    gm.w00 = (1.f - wy) * (1.f - wx) * vy0 * vx0;
    gm.w01 = (1.f - wy) * wx * vy0 * vx1;
    gm.w10 = wy * (1.f - wx) * vy1 * vx0;
    gm.w11 = wy * wx * vy1 * vx1;
    int cy0 = min(max(iy0, 0), H_ - 1), cy1 = min(max(iy1, 0), H_ - 1);
    int cx0 = min(max(ix0, 0), W_ - 1), cx1 = min(max(ix1, 0), W_ - 1);
    int choff = (half * 32 + cq * 8) * HWsz;
    gm.o00 = choff + cy0 * W_ + cx0;
    gm.o01 = choff + cy0 * W_ + cx1;
    gm.o10 = choff + cy1 * W_ + cx0;
    gm.o11 = choff + cy1 * W_ + cx1;
    gm.base = (g == 0) ? xA : (g == 1) ? xB : (g == 2) ? xC : xC + (size_t)64 * HWsz;
    return gm;
}

#define GATHER(J, Cv) do { \
    Cv.x = gm.base[gm.o00 + (J) * HWsz]; \
    Cv.y = gm.base[gm.o01 + (J) * HWsz]; \
    Cv.z = gm.base[gm.o10 + (J) * HWsz]; \
    Cv.w = gm.base[gm.o11 + (J) * HWsz]; \
} while (0)

#define COMB(Cv, IDX) \
    a[IDX] = (short)f2bf(fmaf(w00c, Cv.x, fmaf(w01c, Cv.y, fmaf(w10c, Cv.z, w11c * Cv.w))))

template<bool USE_WS>
__global__ __launch_bounds__(128, 3) void deform_kernel(
    const float* __restrict__ x0, const float* __restrict__ x1,
    const float* __restrict__ x2,
    const float* __restrict__ w_off, const float* __restrict__ b_off,
    const float* __restrict__ w_def, const unsigned short* __restrict__ w2,
    float* __restrict__ out)
{
    __shared__ float off_lds[2][72 * 16];

    const int tid  = threadIdx.x;
    const int lane = tid & 63;
    const int wv   = tid >> 6;
    const int bid  = ((blockIdx.x & 7) << 8) | (blockIdx.x >> 3);
    const int nh   = wv;
    const int ws_  = bid & 15;
    const int h    = (bid >> 4) & 63;
    const int b    = bid >> 10;
    const int p    = lane & 15;
    const int cq   = lane >> 4;
    const int wbase = ws_ * 16;
    const int pix  = h * W_ + wbase;

    const float* xA = x0 + (size_t)b * 64  * HWsz;
    const float* xB = x1 + (size_t)b * 64  * HWsz;
    const float* xC = x2 + (size_t)b * 128 * HWsz;

    f32x4 oa[5];
    #pragma unroll
    for (int t = 0; t < 5; ++t) {
        int o = t * 16 + p;
        float bv = (o < 72) ? b_off[o] : 0.f;
        oa[t][0] = bv; oa[t][1] = bv; oa[t][2] = bv; oa[t][3] = bv;
    }
    #pragma unroll
    for (int c8 = 0; c8 < 8; ++c8) {
        const float* src = (c8 < 2) ? xA + (size_t)c8 * 32 * HWsz
                         : (c8 < 4) ? xB + (size_t)(c8 - 2) * 32 * HWsz
                                    : xC + (size_t)(c8 - 4) * 32 * HWsz;
        s16x8 a;
        #pragma unroll
        for (int j = 0; j < 8; ++j)
            a[j] = (short)f2bf(src[(cq * 8 + j) * HWsz + pix + p]);
        #pragma unroll
        for (int t = 0; t < 5; ++t) {
            int o = t * 16 + p;
            s16x8 bf;
            if (USE_WS) {
                bf = *(const s16x8*)(w2 + WMAIN_ELEMS + (size_t)(c8 * 5 + t) * 512 + lane * 8);
            } else {
                #pragma unroll
                for (int j = 0; j < 8; ++j)
                    bf[j] = (o < 72) ? (short)f2bf(w_off[o * 256 + c8 * 32 + cq * 8 + j])
                                     : (short)0;
            }
            oa[t] = __builtin_amdgcn_mfma_f32_16x16x32_bf16(a, bf, oa[t], 0, 0, 0);
        }
    }
    #pragma unroll
    for (int t = 0; t < 5; ++t) {
        int o = t * 16 + p;
        if (o < 72) {
            #pragma unroll
            for (int r = 0; r < 4; ++r)
                off_lds[wv][o * 16 + cq * 4 + r] = oa[t][r];
        }
    }

    f32x4 acc0={0,0,0,0},acc1={0,0,0,0},acc2={0,0,0,0},acc3={0,0,0,0};
    f32x4 acc4={0,0,0,0},acc5={0,0,0,0},acc6={0,0,0,0},acc7={0,0,0,0};
    const float* offp = &off_lds[wv][0];

    for (int gkh = 0; gkh < 72; ++gkh) {
        Geom gm = make_geom(gkh, offp, h, wbase, p, cq, xA, xB, xC);
        float4 c0, c1, c2, c3, c4, c5, c6, c7;
        GATHER(0, c0); GATHER(1, c1); GATHER(2, c2); GATHER(3, c3);
        GATHER(4, c4); GATHER(5, c5); GATHER(6, c6); GATHER(7, c7);
        float w00c = gm.w00, w01c = gm.w01, w10c = gm.w10, w11c = gm.w11;
        s16x8 a;
        COMB(c0, 0); COMB(c1, 1); COMB(c2, 2); COMB(c3, 3);
        COMB(c4, 4); COMB(c5, 5); COMB(c6, 6); COMB(c7, 7);
        const int half = gkh & 1, gk = gkh >> 1;
        const int k = gk % 9, g = gk / 9;
        const int cbase = g * 64 + half * 32 + cq * 8;
        f32x4* accp[8] = {&acc0,&acc1,&acc2,&acc3,&acc4,&acc5,&acc6,&acc7};
        #pragma unroll
        for (int t = 0; t < 8; ++t) {
            int oc = nh * 128 + t * 16 + p;
            s16x8 bf;
            if (USE_WS) {
                bf = *(const s16x8*)(w2 + gkh * 8192 + nh * 4096 + t * 512 + lane * 8);
            } else {
                #pragma unroll
                for (int j = 0; j < 8; ++j)
                    bf[j] = (short)f2bf(w_def[(size_t)oc * 2304 + (size_t)(cbase + j) * 9 + k]);
            }
            *accp[t] = __builtin_amdgcn_mfma_f32_16x16x32_bf16(a, bf, *accp[t], 0, 0, 0);
        }
    }

    const size_t obase = (size_t)b * OC_ * HWsz + (size_t)h * W_ + wbase + cq * 4;
    f32x4 accs[8] = {acc0, acc1, acc2, acc3, acc4, acc5, acc6, acc7};
    #pragma unroll
    for (int t = 0; t < 8; ++t) {
        int oc = nh * 128 + t * 16 + p;
        float4 r;
        r.x = fmaxf(accs[t][0], 0.f);
        r.y = fmaxf(accs[t][1], 0.f);
        r.z = fmaxf(accs[t][2], 0.f);
        r.w = fmaxf(accs[t][3], 0.f);
        *(float4*)(out + obase + (size_t)oc * HWsz) = r;
    }
}

extern "C" void kernel_launch(void* const* d_in, const int* in_sizes, int n_in,
                              void* d_out, int out_size, void* d_ws, size_t ws_size,
                              hipStream_t stream) {
    const float* x0    = (const float*)d_in[0];
    const float* x1    = (const float*)d_in[1];
    const float* x2    = (const float*)d_in[2];
    const float* w_off = (const float*)d_in[3];
    const float* b_off = (const float*)d_in[4];
    const float* w_def = (const float*)d_in[5];
    float* out = (float*)d_out;

    const size_t w2_bytes   = (size_t)(WMAIN_ELEMS + WOFFB_ELEMS) * 2;
    const size_t full_bytes = (XT_ELEMS + WMAIN_ELEMS + WOFFB_ELEMS) * 2;   // ~18 MB

    if (ws_size >= full_bytes) {
        unsigned short* xt = (unsigned short*)d_ws;
        unsigned short* w2 = xt + XT_ELEMS;
        hipLaunchKernelGGL(xprep_kernel, dim3(512), dim3(256), 0, stream, x0, x1, x2, xt);
        hipLaunchKernelGGL(wprep_kernel, dim3((WMAIN_ELEMS + WOFFB_ELEMS) / 256), dim3(256),
                           0, stream, w_def, w_off, w2);
        hipLaunchKernelGGL(deform64_kernel, dim3(512), dim3(512), 0, stream,
                           xt, b_off, w2, out);
    } else if (ws_size >= w2_bytes) {
        unsigned short* w2 = (unsigned short*)d_ws;
        hipLaunchKernelGGL(wprep_kernel, dim3((WMAIN_ELEMS + WOFFB_ELEMS) / 256), dim3(256),
                           0, stream, w_def, w_off, w2);
        hipLaunchKernelGGL((deform_kernel<true>), dim3(2048), dim3(128), 0, stream,
                           x0, x1, x2, w_off, b_off, w_def, w2, out);
    } else {
        hipLaunchKernelGGL((deform_kernel<false>), dim3(2048), dim3(128), 0, stream,
                           x0, x1, x2, w_off, b_off, w_def, (const unsigned short*)nullptr, out);
    }
}